// Round 1
// 278.920 us; speedup vs baseline: 1.0016x; 1.0016x over previous
//
#include <hip/hip_runtime.h>
#include <hip/hip_bf16.h>

typedef __bf16 bf16;
typedef __bf16 bf16x8 __attribute__((ext_vector_type(8)));
typedef __bf16 bf16x4 __attribute__((ext_vector_type(4)));
typedef float f32x4 __attribute__((ext_vector_type(4)));

#define B_   4
#define T_   2048
#define DM_  1024
#define DH_  1024
#define MROWS 8192

// ---------------------------------------------------------------------------
// fp32 -> bf16, 32 elems/thread: 8 independent dwordx4 loads in flight,
// 4 bf16x8 stores. Block covers 8192 floats (2048 float4).
// ---------------------------------------------------------------------------
struct CvtJob { const float* src; bf16* dst; int nf4; };
struct CvtArgs { CvtJob job[7]; };

__global__ __launch_bounds__(256) void cvt_kernel(CvtArgs args) {
  CvtJob jb = args.job[blockIdx.y];
  int base = blockIdx.x * 2048;
  if (base >= jb.nf4) return;
  int t2 = threadIdx.x * 2;
  const float4* s = (const float4*)jb.src;
  float4 a[4][2];
#pragma unroll
  for (int u = 0; u < 4; ++u) {
    a[u][0] = s[base + u * 512 + t2];
    a[u][1] = s[base + u * 512 + t2 + 1];
  }
#pragma unroll
  for (int u = 0; u < 4; ++u) {
    bf16x8 o;
    o[0] = (bf16)a[u][0].x; o[1] = (bf16)a[u][0].y;
    o[2] = (bf16)a[u][0].z; o[3] = (bf16)a[u][0].w;
    o[4] = (bf16)a[u][1].x; o[5] = (bf16)a[u][1].y;
    o[6] = (bf16)a[u][1].z; o[7] = (bf16)a[u][1].w;
    *(bf16x8*)(jb.dst + ((size_t)base + u * 512 + t2) * 4) = o;
  }
}

// ---------------------------------------------------------------------------
// C[M,N] = A[M,K] * B[N,K]^T, all-bf16. m97 structure: 128x128 tile, BK=64,
// 4 waves 2x2, 4x4 MFMA 16x16x32, global_load_lds w=16, XOR-swizzled LDS
// (0 bank conflicts). Async staging is load-bearing: r3's sync
// load->cvt->ds_write cost +40% — do not fuse fp32 conversion here.
// R1: staging addresses strength-reduced — uniform SGPR base bumped +128B
// per K-step (SALU), 4 loop-invariant 32-bit lane offsets shared by A/B.
// Prior version recomputed 8x 64-bit per-lane addresses each K-step
// (VALUBusy 42% > MfmaUtil 27% — VALU was the critical pipe).
// Epilogue mode: 0 = fp32; 1 = bf16(sigmoid(acc)); 2 = bf16(acc).
// XCD swizzle (gridDim.x==8, gridDim.y%8==0): blocks sharing tileM land on
// one XCD so A rows are fetched ~once per XCD.
// ---------------------------------------------------------------------------
struct GemmJob { const bf16* A; const bf16* Bw; float* Cf; bf16* Cb; int mode; };
struct GemmArgs { GemmJob job[4]; int N; int K; };

__global__ __launch_bounds__(256) void gemm_bt(GemmArgs ga) {
  const GemmJob jb = ga.job[blockIdx.z];
  const int N = ga.N, K = ga.K;
  __shared__ bf16 As[128 * 64];
  __shared__ bf16 Bs[128 * 64];

  const int tid  = threadIdx.x;
  const int lane = tid & 63;
  const int wave = tid >> 6;
  const int wm   = (wave >> 1) * 64;
  const int wn   = (wave & 1) * 64;

  const int f   = blockIdx.y * 8 + blockIdx.x;
  const int xcd = f & 7;
  const int j   = f >> 3;
  const int bn  = j & 7;
  const int bm  = (j >> 3) * 8 + xcd;
  const int tileM = bm * 128;
  const int tileN = bn * 128;

  f32x4 acc[4][4] = {};

  const int sr = lane >> 3;
  const int sc = (lane & 7) ^ sr;

  // Uniform 64-bit bases (SGPR pair), advanced by scalar adds per K-step.
  // Per-lane 32-bit byte offsets are loop-invariant and shared by A and B.
  const char* pa = (const char*)(jb.A  + (size_t)tileM * K);
  const char* pb = (const char*)(jb.Bw + (size_t)tileN * K);
  unsigned int off[4];
#pragma unroll
  for (int l = 0; l < 4; ++l)
    off[l] = (unsigned int)((((wave * 4 + l) * 8 + sr) * K + sc * 8) * 2);

  const int quad = lane >> 4;

  for (int k0 = 0; k0 < K; k0 += 64) {
#pragma unroll
    for (int l = 0; l < 4; ++l) {
      __builtin_amdgcn_global_load_lds(
          (const __attribute__((address_space(1))) void*)(pa + off[l]),
          (__attribute__((address_space(3))) void*)&As[(wave * 4 + l) * 512],
          16, 0, 0);
      __builtin_amdgcn_global_load_lds(
          (const __attribute__((address_space(1))) void*)(pb + off[l]),
          (__attribute__((address_space(3))) void*)&Bs[(wave * 4 + l) * 512],
          16, 0, 0);
    }
    pa += 128;  // 64 bf16 K-advance
    pb += 128;
    __syncthreads();

#pragma unroll
    for (int s = 0; s < 2; ++s) {
      bf16x8 af[4], bfr[4];
#pragma unroll
      for (int mt = 0; mt < 4; ++mt) {
        int row = wm + mt * 16 + (lane & 15);
        int chunk = (s * 4 + quad) ^ (row & 7);
        af[mt] = *(const bf16x8*)&As[row * 64 + chunk * 8];
      }
#pragma unroll
      for (int nt = 0; nt < 4; ++nt) {
        int row = wn + nt * 16 + (lane & 15);
        int chunk = (s * 4 + quad) ^ (row & 7);
        bfr[nt] = *(const bf16x8*)&Bs[row * 64 + chunk * 8];
      }
#pragma unroll
      for (int mt = 0; mt < 4; ++mt)
#pragma unroll
        for (int nt = 0; nt < 4; ++nt)
          acc[mt][nt] = __builtin_amdgcn_mfma_f32_16x16x32_bf16(
              af[mt], bfr[nt], acc[mt][nt], 0, 0, 0);
    }
    __syncthreads();
  }

  const int cn = lane & 15;
  const int cr = (lane >> 4) * 4;
  if (jb.mode == 0) {
#pragma unroll
    for (int mt = 0; mt < 4; ++mt)
#pragma unroll
      for (int nt = 0; nt < 4; ++nt)
#pragma unroll
        for (int r = 0; r < 4; ++r) {
          int row = tileM + wm + mt * 16 + cr + r;
          int col = tileN + wn + nt * 16 + cn;
          jb.Cf[(size_t)row * N + col] = acc[mt][nt][r];
        }
  } else if (jb.mode == 1) {
#pragma unroll
    for (int mt = 0; mt < 4; ++mt)
#pragma unroll
      for (int nt = 0; nt < 4; ++nt)
#pragma unroll
        for (int r = 0; r < 4; ++r) {
          int row = tileM + wm + mt * 16 + cr + r;
          int col = tileN + wn + nt * 16 + cn;
          jb.Cb[(size_t)row * N + col] =
              (bf16)(1.f / (1.f + __expf(-acc[mt][nt][r])));
        }
  } else {
#pragma unroll
    for (int mt = 0; mt < 4; ++mt)
#pragma unroll
      for (int nt = 0; nt < 4; ++nt)
#pragma unroll
        for (int r = 0; r < 4; ++r) {
          int row = tileM + wm + mt * 16 + cr + r;
          int col = tileN + wn + nt * 16 + cn;
          jb.Cb[(size_t)row * N + col] = (bf16)acc[mt][nt][r];
        }
  }
}

// ---------------------------------------------------------------------------
// Pass A: per-block partial reduction over 8 j-rows, atomic-free.
// m[j,d]=max_b K; w=exp(K-m); partial num/den summed over the block's j's.
// 256 blocks (1/CU). Thread-half h covers j in [blk*8+h*4, +4), 8 d each.
// Halves merge via LDS [idx][dt] (conflict-free), half 0 stores partials:
// part[blk][0:4096]=num(b,d), part[blk][4096:8192]=den(b,d).
// ---------------------------------------------------------------------------
__global__ __launch_bounds__(256) void reduce_kv(
    const bf16* __restrict__ Kb, const bf16* __restrict__ Vb,
    float* __restrict__ part) {
  __shared__ float lds[64 * 128];
  const int t = threadIdx.x;
  const int half = t >> 7;
  const int dt = t & 127;
  const int d = dt * 8;
  const int j0 = blockIdx.x * 8 + half * 4;
  const size_t bs = (size_t)T_ * DH_;
  float n[4][8] = {}, e[4][8] = {};
  for (int jj = j0; jj < j0 + 4; ++jj) {
    size_t off = (size_t)jj * DH_ + d;
    bf16x8 kk[4], vv[4];
#pragma unroll
    for (int b = 0; b < 4; ++b) {
      kk[b] = *(const bf16x8*)(Kb + off + b * bs);
      vv[b] = *(const bf16x8*)(Vb + off + b * bs);
    }
#pragma unroll
    for (int c = 0; c < 8; ++c) {
      float k0 = (float)kk[0][c], k1 = (float)kk[1][c];
      float k2 = (float)kk[2][c], k3 = (float)kk[3][c];
      float m = fmaxf(fmaxf(k0, k1), fmaxf(k2, k3));
      float w0 = __expf(k0 - m), w1 = __expf(k1 - m);
      float w2 = __expf(k2 - m), w3 = __expf(k3 - m);
      e[0][c] += w0; e[1][c] += w1; e[2][c] += w2; e[3][c] += w3;
      n[0][c] += w0 * (float)vv[0][c];
      n[1][c] += w1 * (float)vv[1][c];
      n[2][c] += w2 * (float)vv[2][c];
      n[3][c] += w3 * (float)vv[3][c];
    }
  }
  if (half) {
#pragma unroll
    for (int b = 0; b < 4; ++b)
#pragma unroll
      for (int c = 0; c < 8; ++c) {
        lds[(b * 8 + c) * 128 + dt] = n[b][c];
        lds[(32 + b * 8 + c) * 128 + dt] = e[b][c];
      }
  }
  __syncthreads();
  if (!half) {
    float* po = part + (size_t)blockIdx.x * 8192;
#pragma unroll
    for (int b = 0; b < 4; ++b)
#pragma unroll
      for (int c = 0; c < 8; ++c) {
        po[b * 1024 + d + c] = n[b][c] + lds[(b * 8 + c) * 128 + dt];
        po[4096 + b * 1024 + d + c] = e[b][c] + lds[(32 + b * 8 + c) * 128 + dt];
      }
  }
}

// ---------------------------------------------------------------------------
// Pass B: numden[slot] = sum over 256 blocks of part[i][slot].
// 64 blocks x 256 threads; thread-half sums 128 partials (unroll-8 ILP),
// halves merge via LDS. Coalesced: consecutive threads = consecutive slots.
// ---------------------------------------------------------------------------
__global__ __launch_bounds__(256) void finish_kv(
    const float* __restrict__ part, float* __restrict__ numden) {
  __shared__ float lds[128];
  const int t = threadIdx.x;
  const int half = t >> 7;
  const int sl = t & 127;
  const int slot = blockIdx.x * 128 + sl;
  float s = 0.f;
  for (int i = half * 128; i < half * 128 + 128; i += 8) {
#pragma unroll
    for (int u = 0; u < 8; ++u)
      s += part[(size_t)(i + u) * 8192 + slot];
  }
  if (half) lds[sl] = s;
  __syncthreads();
  if (!half) numden[slot] = s + lds[sl];
}

// ---------------------------------------------------------------------------
// Wo_b[b][m][h] = Wo[m][h] * num[b,h]/den[b,h]  (ratio folded into weight;
// exact: out[b] = (sig(Q[b]) ⊙ r[b]) @ Wo^T = sig(Q[b]) @ (Wo ⊙ r[b])^T
// since num/den are i-independent). Replaces the 32MB mul_ratio pass.
// grid (512, 4): b = blockIdx.y, 2048 bf16 per block.
// ---------------------------------------------------------------------------
__global__ __launch_bounds__(256) void scale_wo(
    const bf16* __restrict__ Wo, const float* __restrict__ numden,
    bf16* __restrict__ out4) {
  const int b = blockIdx.y;
  size_t i = ((size_t)blockIdx.x * 256 + threadIdx.x) * 8;
  int h = (int)(i & (DH_ - 1));
  bf16x8 w = *(const bf16x8*)(Wo + i);
  const float* nu = numden + b * DH_ + h;
  const float* de = numden + 4096 + b * DH_ + h;
  float4 n0 = *(const float4*)nu;
  float4 n1 = *(const float4*)(nu + 4);
  float4 d0 = *(const float4*)de;
  float4 d1 = *(const float4*)(de + 4);
  bf16x8 o;
  o[0] = (bf16)((float)w[0] * n0.x / d0.x);
  o[1] = (bf16)((float)w[1] * n0.y / d0.y);
  o[2] = (bf16)((float)w[2] * n0.z / d0.z);
  o[3] = (bf16)((float)w[3] * n0.w / d0.w);
  o[4] = (bf16)((float)w[4] * n1.x / d1.x);
  o[5] = (bf16)((float)w[5] * n1.y / d1.y);
  o[6] = (bf16)((float)w[6] * n1.z / d1.z);
  o[7] = (bf16)((float)w[7] * n1.w / d1.w);
  *(bf16x8*)(out4 + (size_t)b * ((size_t)DM_ * DH_) + i) = o;
}

// ---------------------------------------------------------------------------
extern "C" void kernel_launch(void* const* d_in, const int* in_sizes, int n_in,
                              void* d_out, int out_size, void* d_ws, size_t ws_size,
                              hipStream_t stream) {
  const float* q  = (const float*)d_in[0];
  const float* k  = (const float*)d_in[1];
  const float* v  = (const float*)d_in[2];
  const float* Wq = (const float*)d_in[3];
  const float* Wk = (const float*)d_in[4];
  const float* Wv = (const float*)d_in[5];
  const float* Wo = (const float*)d_in[6];
  // d_in[7] = W_bias mathematically unused (exp_pos_bias == all-ones).
  float* out = (float*)d_out;

  char* ws = (char*)d_ws;
  size_t off = 0;
  auto alloc = [&](size_t bytes) {
    char* p = ws + off;
    off += (bytes + 255) & ~(size_t)255;
    return p;
  };
  const size_t actN = (size_t)MROWS * DM_;   // 8388608
  const size_t wN   = (size_t)DH_ * DM_;     // 1048576

  bf16* qb  = (bf16*)alloc(actN * 2);
  bf16* kb  = (bf16*)alloc(actN * 2);
  bf16* vb  = (bf16*)alloc(actN * 2);
  bf16* Wqb = (bf16*)alloc(wN * 2);
  bf16* Wkb = (bf16*)alloc(wN * 2);
  bf16* Wvb = (bf16*)alloc(wN * 2);
  bf16* Wob = (bf16*)alloc(wN * 2);
  bf16* Kb  = (bf16*)alloc(actN * 2);
  bf16* Vb  = (bf16*)alloc(actN * 2);
  bf16* Yb  = (bf16*)alloc(actN * 2);
  float* part = (float*)alloc((size_t)256 * 8192 * 4);   // 8 MB partials
  float* numden = (float*)alloc(8192 * 4);
  // Wob4 (4 batch-scaled Wo copies, 8MB) aliases part: part is dead after
  // finish_kv, scale_wo runs after it (stream-ordered).
  bf16* Wob4 = (bf16*)part;

  // 1) fp32 -> bf16 (activations + all 4 weights)
  CvtArgs ca;
  ca.job[0] = {q,  qb,  (int)(actN / 4)};
  ca.job[1] = {k,  kb,  (int)(actN / 4)};
  ca.job[2] = {v,  vb,  (int)(actN / 4)};
  ca.job[3] = {Wq, Wqb, (int)(wN / 4)};
  ca.job[4] = {Wk, Wkb, (int)(wN / 4)};
  ca.job[5] = {Wv, Wvb, (int)(wN / 4)};
  ca.job[6] = {Wo, Wob, (int)(wN / 4)};
  cvt_kernel<<<dim3(actN / 4 / 2048, 7), 256, 0, stream>>>(ca);

  // 2) merged K/V/Q projections (async bf16 staging; Q epilogue = sigmoid)
  GemmArgs g1;
  g1.N = DH_; g1.K = DM_;
  g1.job[0] = {kb, Wkb, nullptr, Kb, 2};
  g1.job[1] = {vb, Wvb, nullptr, Vb, 2};
  g1.job[2] = {qb, Wqb, nullptr, Yb, 1};
  g1.job[3] = {nullptr, nullptr, nullptr, nullptr, 0};
  gemm_bt<<<dim3(8, MROWS / 128, 3), 256, 0, stream>>>(g1);

  // 3) two-pass atomic-free reduction
  reduce_kv<<<dim3(256), 256, 0, stream>>>(Kb, Vb, part);
  finish_kv<<<dim3(64), 256, 0, stream>>>(part, numden);

  // 4) fold ratio into per-batch Wo copies (replaces 32MB mul_ratio pass)
  scale_wo<<<dim3(512, 4), 256, 0, stream>>>(Wob, numden, Wob4);

  // 5) out[b] = sig(Q[b]) @ (Wo ⊙ r[b])^T  — 4 per-batch jobs, fp32 out
  GemmArgs g2;
  g2.N = DM_; g2.K = DH_;
  for (int b = 0; b < 4; ++b) {
    g2.job[b] = {Yb + (size_t)b * ((size_t)T_ * DH_),
                 Wob4 + (size_t)b * wN,
                 out + (size_t)b * ((size_t)T_ * DM_),
                 nullptr, 0};
  }
  gemm_bt<<<dim3(8, 16, 4), 256, 0, stream>>>(g2);
}

// Round 2
// 274.286 us; speedup vs baseline: 1.0186x; 1.0169x over previous
//
#include <hip/hip_runtime.h>
#include <hip/hip_bf16.h>

typedef __bf16 bf16;
typedef __bf16 bf16x8 __attribute__((ext_vector_type(8)));
typedef __bf16 bf16x4 __attribute__((ext_vector_type(4)));
typedef float f32x4 __attribute__((ext_vector_type(4)));
typedef float f32x16 __attribute__((ext_vector_type(16)));

#define B_   4
#define T_   2048
#define DM_  1024
#define DH_  1024
#define MROWS 8192

// ---------------------------------------------------------------------------
// fp32 -> bf16, 32 elems/thread: 8 independent dwordx4 loads in flight,
// 4 bf16x8 stores. Block covers 8192 floats (2048 float4).
// ---------------------------------------------------------------------------
struct CvtJob { const float* src; bf16* dst; int nf4; };
struct CvtArgs { CvtJob job[7]; };

__global__ __launch_bounds__(256) void cvt_kernel(CvtArgs args) {
  CvtJob jb = args.job[blockIdx.y];
  int base = blockIdx.x * 2048;
  if (base >= jb.nf4) return;
  int t2 = threadIdx.x * 2;
  const float4* s = (const float4*)jb.src;
  float4 a[4][2];
#pragma unroll
  for (int u = 0; u < 4; ++u) {
    a[u][0] = s[base + u * 512 + t2];
    a[u][1] = s[base + u * 512 + t2 + 1];
  }
#pragma unroll
  for (int u = 0; u < 4; ++u) {
    bf16x8 o;
    o[0] = (bf16)a[u][0].x; o[1] = (bf16)a[u][0].y;
    o[2] = (bf16)a[u][0].z; o[3] = (bf16)a[u][0].w;
    o[4] = (bf16)a[u][1].x; o[5] = (bf16)a[u][1].y;
    o[6] = (bf16)a[u][1].z; o[7] = (bf16)a[u][1].w;
    *(bf16x8*)(jb.dst + ((size_t)base + u * 512 + t2) * 4) = o;
  }
}

// ---------------------------------------------------------------------------
// C[M,N] = A[M,K] * B[N,K]^T, all-bf16. m97 structure: MTx64-row x 128-col
// tile, BK=64, 4 waves 2x2, global_load_lds w=16, XOR-swizzled LDS
// (0 bank conflicts measured). Async staging is load-bearing (r3 lesson).
// R2: MFMA 16x16x32 -> 32x32x16 (4061 vs 3378 FLOP/cyc measured pipe rate,
// half the issue slots; staging/swizzle untouched). Template MT: per-wave
// m-tiles of 32 rows. MT=2 -> 128x128 tile (projections); MT=1 -> 64x128
// tile for the output GEMM (1024 blocks = 4/CU vs 2/CU — gemm2 had half
// of gemm1's wave-level latency hiding).
// C/D layout (m74/m101-verified): col=lane&31, row=(reg&3)+8(reg>>2)+4(lane>>5).
// A/B frag: row/col=lane&31, k=(lane>>5)*8+i per 16-k slice.
// Epilogue mode: 0 = fp32; 1 = bf16(sigmoid(acc)); 2 = bf16(acc).
// XCD swizzle (gridDim.x==8, gridDim.y%8==0): blocks sharing tileM land on
// one XCD so A rows are fetched ~once per XCD.
// ---------------------------------------------------------------------------
struct GemmJob { const bf16* A; const bf16* Bw; float* Cf; bf16* Cb; int mode; };
struct GemmArgs { GemmJob job[4]; int N; int K; };

template <int MT>
__global__ __launch_bounds__(256) void gemm_bt(GemmArgs ga) {
  const GemmJob jb = ga.job[blockIdx.z];
  const int N = ga.N, K = ga.K;
  constexpr int TM = MT * 64;               // tile rows
  __shared__ __align__(16) bf16 As[TM * 64];
  __shared__ __align__(16) bf16 Bs[128 * 64];

  const int tid  = threadIdx.x;
  const int lane = tid & 63;
  const int wave = tid >> 6;
  const int wm   = (wave >> 1) * (MT * 32);
  const int wn   = (wave & 1) * 64;

  const int f   = blockIdx.y * 8 + blockIdx.x;
  const int xcd = f & 7;
  const int j   = f >> 3;
  const int bn  = j & 7;
  const int bm  = (j >> 3) * 8 + xcd;
  const int tileM = bm * TM;
  const int tileN = bn * 128;

  f32x16 acc[MT][2] = {};

  const int sr = lane >> 3;
  const int sc = (lane & 7) ^ sr;

  // Uniform 64-bit bases (SGPR pair), advanced by scalar adds per K-step.
  const char* pa = (const char*)(jb.A  + (size_t)tileM * K);
  const char* pb = (const char*)(jb.Bw + (size_t)tileN * K);
  unsigned int offA[MT * 2], offB[4];
#pragma unroll
  for (int l = 0; l < MT * 2; ++l)
    offA[l] = (unsigned int)((((wave * (MT * 2) + l) * 8 + sr) * K + sc * 8) * 2);
#pragma unroll
  for (int l = 0; l < 4; ++l)
    offB[l] = (unsigned int)((((wave * 4 + l) * 8 + sr) * K + sc * 8) * 2);

  const int half = lane >> 5;   // k-group within 16-slice
  const int rc   = lane & 31;   // row (A) / col (B) within 32-tile

  for (int k0 = 0; k0 < K; k0 += 64) {
#pragma unroll
    for (int l = 0; l < MT * 2; ++l)
      __builtin_amdgcn_global_load_lds(
          (const __attribute__((address_space(1))) void*)(pa + offA[l]),
          (__attribute__((address_space(3))) void*)&As[(wave * (MT * 2) + l) * 512],
          16, 0, 0);
#pragma unroll
    for (int l = 0; l < 4; ++l)
      __builtin_amdgcn_global_load_lds(
          (const __attribute__((address_space(1))) void*)(pb + offB[l]),
          (__attribute__((address_space(3))) void*)&Bs[(wave * 4 + l) * 512],
          16, 0, 0);
    pa += 128;  // 64 bf16 K-advance
    pb += 128;
    __syncthreads();

#pragma unroll
    for (int s = 0; s < 2; ++s) {        // two 32-k halves; ks = s*2 + kk
      bf16x8 af[MT][2], bfr[2][2];
#pragma unroll
      for (int mt = 0; mt < MT; ++mt)
#pragma unroll
        for (int kk = 0; kk < 2; ++kk) {
          int row = wm + mt * 32 + rc;
          int chunk = ((s * 2 + kk) * 2 + half) ^ (row & 7);
          af[mt][kk] = *(const bf16x8*)&As[row * 64 + chunk * 8];
        }
#pragma unroll
      for (int nt = 0; nt < 2; ++nt)
#pragma unroll
        for (int kk = 0; kk < 2; ++kk) {
          int row = wn + nt * 32 + rc;
          int chunk = ((s * 2 + kk) * 2 + half) ^ (row & 7);
          bfr[nt][kk] = *(const bf16x8*)&Bs[row * 64 + chunk * 8];
        }
#pragma unroll
      for (int kk = 0; kk < 2; ++kk)
#pragma unroll
        for (int mt = 0; mt < MT; ++mt)
#pragma unroll
          for (int nt = 0; nt < 2; ++nt)
            acc[mt][nt] = __builtin_amdgcn_mfma_f32_32x32x16_bf16(
                af[mt][kk], bfr[nt][kk], acc[mt][nt], 0, 0, 0);
    }
    __syncthreads();
  }

  // C/D: col = lane&31, row = (reg&3) + 8*(reg>>2) + 4*(lane>>5)
  const int cn    = rc;
  const int rbase = half * 4;
  if (jb.mode == 0) {
#pragma unroll
    for (int mt = 0; mt < MT; ++mt)
#pragma unroll
      for (int nt = 0; nt < 2; ++nt)
#pragma unroll
        for (int r = 0; r < 16; ++r) {
          int row = tileM + wm + mt * 32 + rbase + (r & 3) + 8 * (r >> 2);
          int col = tileN + wn + nt * 32 + cn;
          jb.Cf[(size_t)row * N + col] = acc[mt][nt][r];
        }
  } else if (jb.mode == 1) {
#pragma unroll
    for (int mt = 0; mt < MT; ++mt)
#pragma unroll
      for (int nt = 0; nt < 2; ++nt)
#pragma unroll
        for (int r = 0; r < 16; ++r) {
          int row = tileM + wm + mt * 32 + rbase + (r & 3) + 8 * (r >> 2);
          int col = tileN + wn + nt * 32 + cn;
          jb.Cb[(size_t)row * N + col] =
              (bf16)(1.f / (1.f + __expf(-acc[mt][nt][r])));
        }
  } else {
#pragma unroll
    for (int mt = 0; mt < MT; ++mt)
#pragma unroll
      for (int nt = 0; nt < 2; ++nt)
#pragma unroll
        for (int r = 0; r < 16; ++r) {
          int row = tileM + wm + mt * 32 + rbase + (r & 3) + 8 * (r >> 2);
          int col = tileN + wn + nt * 32 + cn;
          jb.Cb[(size_t)row * N + col] = (bf16)acc[mt][nt][r];
        }
  }
}

// ---------------------------------------------------------------------------
// Pass A: per-block partial reduction over 8 j-rows, atomic-free.
// m[j,d]=max_b K; w=exp(K-m); partial num/den summed over the block's j's.
// 256 blocks (1/CU). Thread-half h covers j in [blk*8+h*4, +4), 8 d each.
// Halves merge via LDS [idx][dt] (conflict-free), half 0 stores partials:
// part[blk][0:4096]=num(b,d), part[blk][4096:8192]=den(b,d).
// ---------------------------------------------------------------------------
__global__ __launch_bounds__(256) void reduce_kv(
    const bf16* __restrict__ Kb, const bf16* __restrict__ Vb,
    float* __restrict__ part) {
  __shared__ float lds[64 * 128];
  const int t = threadIdx.x;
  const int half = t >> 7;
  const int dt = t & 127;
  const int d = dt * 8;
  const int j0 = blockIdx.x * 8 + half * 4;
  const size_t bs = (size_t)T_ * DH_;
  float n[4][8] = {}, e[4][8] = {};
  for (int jj = j0; jj < j0 + 4; ++jj) {
    size_t off = (size_t)jj * DH_ + d;
    bf16x8 kk[4], vv[4];
#pragma unroll
    for (int b = 0; b < 4; ++b) {
      kk[b] = *(const bf16x8*)(Kb + off + b * bs);
      vv[b] = *(const bf16x8*)(Vb + off + b * bs);
    }
#pragma unroll
    for (int c = 0; c < 8; ++c) {
      float k0 = (float)kk[0][c], k1 = (float)kk[1][c];
      float k2 = (float)kk[2][c], k3 = (float)kk[3][c];
      float m = fmaxf(fmaxf(k0, k1), fmaxf(k2, k3));
      float w0 = __expf(k0 - m), w1 = __expf(k1 - m);
      float w2 = __expf(k2 - m), w3 = __expf(k3 - m);
      e[0][c] += w0; e[1][c] += w1; e[2][c] += w2; e[3][c] += w3;
      n[0][c] += w0 * (float)vv[0][c];
      n[1][c] += w1 * (float)vv[1][c];
      n[2][c] += w2 * (float)vv[2][c];
      n[3][c] += w3 * (float)vv[3][c];
    }
  }
  if (half) {
#pragma unroll
    for (int b = 0; b < 4; ++b)
#pragma unroll
      for (int c = 0; c < 8; ++c) {
        lds[(b * 8 + c) * 128 + dt] = n[b][c];
        lds[(32 + b * 8 + c) * 128 + dt] = e[b][c];
      }
  }
  __syncthreads();
  if (!half) {
    float* po = part + (size_t)blockIdx.x * 8192;
#pragma unroll
    for (int b = 0; b < 4; ++b)
#pragma unroll
      for (int c = 0; c < 8; ++c) {
        po[b * 1024 + d + c] = n[b][c] + lds[(b * 8 + c) * 128 + dt];
        po[4096 + b * 1024 + d + c] = e[b][c] + lds[(32 + b * 8 + c) * 128 + dt];
      }
  }
}

// ---------------------------------------------------------------------------
// Pass B: numden[slot] = sum over 256 blocks of part[i][slot].
// 64 blocks x 256 threads; thread-half sums 128 partials (unroll-8 ILP),
// halves merge via LDS. Coalesced: consecutive threads = consecutive slots.
// ---------------------------------------------------------------------------
__global__ __launch_bounds__(256) void finish_kv(
    const float* __restrict__ part, float* __restrict__ numden) {
  __shared__ float lds[128];
  const int t = threadIdx.x;
  const int half = t >> 7;
  const int sl = t & 127;
  const int slot = blockIdx.x * 128 + sl;
  float s = 0.f;
  for (int i = half * 128; i < half * 128 + 128; i += 8) {
#pragma unroll
    for (int u = 0; u < 8; ++u)
      s += part[(size_t)(i + u) * 8192 + slot];
  }
  if (half) lds[sl] = s;
  __syncthreads();
  if (!half) numden[slot] = s + lds[sl];
}

// ---------------------------------------------------------------------------
// Wo_b[b][m][h] = Wo[m][h] * num[b,h]/den[b,h]  (ratio folded into weight;
// exact: out[b] = (sig(Q[b]) ⊙ r[b]) @ Wo^T = sig(Q[b]) @ (Wo ⊙ r[b])^T
// since num/den are i-independent). grid (512, 4): b = blockIdx.y.
// ---------------------------------------------------------------------------
__global__ __launch_bounds__(256) void scale_wo(
    const bf16* __restrict__ Wo, const float* __restrict__ numden,
    bf16* __restrict__ out4) {
  const int b = blockIdx.y;
  size_t i = ((size_t)blockIdx.x * 256 + threadIdx.x) * 8;
  int h = (int)(i & (DH_ - 1));
  bf16x8 w = *(const bf16x8*)(Wo + i);
  const float* nu = numden + b * DH_ + h;
  const float* de = numden + 4096 + b * DH_ + h;
  float4 n0 = *(const float4*)nu;
  float4 n1 = *(const float4*)(nu + 4);
  float4 d0 = *(const float4*)de;
  float4 d1 = *(const float4*)(de + 4);
  bf16x8 o;
  o[0] = (bf16)((float)w[0] * n0.x / d0.x);
  o[1] = (bf16)((float)w[1] * n0.y / d0.y);
  o[2] = (bf16)((float)w[2] * n0.z / d0.z);
  o[3] = (bf16)((float)w[3] * n0.w / d0.w);
  o[4] = (bf16)((float)w[4] * n1.x / d1.x);
  o[5] = (bf16)((float)w[5] * n1.y / d1.y);
  o[6] = (bf16)((float)w[6] * n1.z / d1.z);
  o[7] = (bf16)((float)w[7] * n1.w / d1.w);
  *(bf16x8*)(out4 + (size_t)b * ((size_t)DM_ * DH_) + i) = o;
}

// ---------------------------------------------------------------------------
extern "C" void kernel_launch(void* const* d_in, const int* in_sizes, int n_in,
                              void* d_out, int out_size, void* d_ws, size_t ws_size,
                              hipStream_t stream) {
  const float* q  = (const float*)d_in[0];
  const float* k  = (const float*)d_in[1];
  const float* v  = (const float*)d_in[2];
  const float* Wq = (const float*)d_in[3];
  const float* Wk = (const float*)d_in[4];
  const float* Wv = (const float*)d_in[5];
  const float* Wo = (const float*)d_in[6];
  // d_in[7] = W_bias mathematically unused (exp_pos_bias == all-ones).
  float* out = (float*)d_out;

  char* ws = (char*)d_ws;
  size_t off = 0;
  auto alloc = [&](size_t bytes) {
    char* p = ws + off;
    off += (bytes + 255) & ~(size_t)255;
    return p;
  };
  const size_t actN = (size_t)MROWS * DM_;   // 8388608
  const size_t wN   = (size_t)DH_ * DM_;     // 1048576

  bf16* qb  = (bf16*)alloc(actN * 2);
  bf16* kb  = (bf16*)alloc(actN * 2);
  bf16* vb  = (bf16*)alloc(actN * 2);
  bf16* Wqb = (bf16*)alloc(wN * 2);
  bf16* Wkb = (bf16*)alloc(wN * 2);
  bf16* Wvb = (bf16*)alloc(wN * 2);
  bf16* Wob = (bf16*)alloc(wN * 2);
  bf16* Kb  = (bf16*)alloc(actN * 2);
  bf16* Vb  = (bf16*)alloc(actN * 2);
  bf16* Yb  = (bf16*)alloc(actN * 2);
  float* part = (float*)alloc((size_t)256 * 8192 * 4);   // 8 MB partials
  float* numden = (float*)alloc(8192 * 4);
  // Wob4 (4 batch-scaled Wo copies, 8MB) aliases part: part is dead after
  // finish_kv, scale_wo runs after it (stream-ordered).
  bf16* Wob4 = (bf16*)part;

  // 1) fp32 -> bf16 (activations + all 4 weights)
  CvtArgs ca;
  ca.job[0] = {q,  qb,  (int)(actN / 4)};
  ca.job[1] = {k,  kb,  (int)(actN / 4)};
  ca.job[2] = {v,  vb,  (int)(actN / 4)};
  ca.job[3] = {Wq, Wqb, (int)(wN / 4)};
  ca.job[4] = {Wk, Wkb, (int)(wN / 4)};
  ca.job[5] = {Wv, Wvb, (int)(wN / 4)};
  ca.job[6] = {Wo, Wob, (int)(wN / 4)};
  cvt_kernel<<<dim3(actN / 4 / 2048, 7), 256, 0, stream>>>(ca);

  // 2) merged K/V/Q projections (async bf16 staging; Q epilogue = sigmoid)
  GemmArgs g1;
  g1.N = DH_; g1.K = DM_;
  g1.job[0] = {kb, Wkb, nullptr, Kb, 2};
  g1.job[1] = {vb, Wvb, nullptr, Vb, 2};
  g1.job[2] = {qb, Wqb, nullptr, Yb, 1};
  g1.job[3] = {nullptr, nullptr, nullptr, nullptr, 0};
  gemm_bt<2><<<dim3(8, MROWS / 128, 3), 256, 0, stream>>>(g1);

  // 3) two-pass atomic-free reduction
  reduce_kv<<<dim3(256), 256, 0, stream>>>(Kb, Vb, part);
  finish_kv<<<dim3(64), 256, 0, stream>>>(part, numden);

  // 4) fold ratio into per-batch Wo copies
  scale_wo<<<dim3(512, 4), 256, 0, stream>>>(Wob, numden, Wob4);

  // 5) out[b] = sig(Q[b]) @ (Wo ⊙ r[b])^T  — 4 per-batch jobs, fp32 out,
  //    64-row tiles (MT=1): 1024 blocks = 4/CU for latency hiding.
  GemmArgs g2;
  g2.N = DM_; g2.K = DH_;
  for (int b = 0; b < 4; ++b) {
    g2.job[b] = {Yb + (size_t)b * ((size_t)T_ * DH_),
                 Wob4 + (size_t)b * wN,
                 out + (size_t)b * ((size_t)T_ * DM_),
                 nullptr, 0};
  }
  gemm_bt<1><<<dim3(8, 32, 4), 256, 0, stream>>>(g2);
}

// Round 3
// 269.490 us; speedup vs baseline: 1.0367x; 1.0178x over previous
//
#include <hip/hip_runtime.h>
#include <hip/hip_bf16.h>

typedef __bf16 bf16;
typedef __bf16 bf16x8 __attribute__((ext_vector_type(8)));
typedef __bf16 bf16x4 __attribute__((ext_vector_type(4)));
typedef float f32x4 __attribute__((ext_vector_type(4)));
typedef float f32x16 __attribute__((ext_vector_type(16)));

#define B_   4
#define T_   2048
#define DM_  1024
#define DH_  1024
#define MROWS 8192

// ---------------------------------------------------------------------------
// fp32 -> bf16, 32 elems/thread: 8 independent dwordx4 loads in flight,
// 4 bf16x8 stores. Block covers 8192 floats (2048 float4).
// ---------------------------------------------------------------------------
struct CvtJob { const float* src; bf16* dst; int nf4; };
struct CvtArgs { CvtJob job[7]; };

__global__ __launch_bounds__(256) void cvt_kernel(CvtArgs args) {
  CvtJob jb = args.job[blockIdx.y];
  int base = blockIdx.x * 2048;
  if (base >= jb.nf4) return;
  int t2 = threadIdx.x * 2;
  const float4* s = (const float4*)jb.src;
  float4 a[4][2];
#pragma unroll
  for (int u = 0; u < 4; ++u) {
    a[u][0] = s[base + u * 512 + t2];
    a[u][1] = s[base + u * 512 + t2 + 1];
  }
#pragma unroll
  for (int u = 0; u < 4; ++u) {
    bf16x8 o;
    o[0] = (bf16)a[u][0].x; o[1] = (bf16)a[u][0].y;
    o[2] = (bf16)a[u][0].z; o[3] = (bf16)a[u][0].w;
    o[4] = (bf16)a[u][1].x; o[5] = (bf16)a[u][1].y;
    o[6] = (bf16)a[u][1].z; o[7] = (bf16)a[u][1].w;
    *(bf16x8*)(jb.dst + ((size_t)base + u * 512 + t2) * 4) = o;
  }
}

// ---------------------------------------------------------------------------
// C[M,N] = A[M,K] * B[N,K]^T, all-bf16. m97 structure: MTx64-row x 128-col
// tile, BK=64, 4 waves 2x2, global_load_lds w=16, MFMA 32x32x16 (R2: 4061
// vs 3378 FLOP/cyc pipe rate, VALUBusy 42->17%).
// R3: swizzle mask widened row&7 -> (row&7)^((row>>3)&7) on BOTH write
// (sc ^= grp&7) and read (chunk ^= (row>>3)&7). R2's lane>>5-based reads
// repeated the same bank-quad pattern in consecutive 16-lane phases ->
// measured exactly 4 conflict-cycles per ds_read_b128 (6.29M/dispatch).
// Widened mask makes lanes 8 apart hit different quads (restores the
// phase-alternation the 16x16 quad pattern had). Async staging is
// load-bearing (r3 lesson) — do not fuse fp32 conversion here.
// C/D layout (m74/m101-verified): col=lane&31, row=(reg&3)+8(reg>>2)+4(lane>>5).
// A/B frag: row/col=lane&31, k=(lane>>5)*8+i per 16-k slice.
// Epilogue mode: 0 = fp32; 1 = bf16(sigmoid(acc)); 2 = bf16(acc).
// XCD swizzle (gridDim.x==8, gridDim.y%8==0): blocks sharing tileM land on
// one XCD so A rows are fetched ~once per XCD.
// ---------------------------------------------------------------------------
struct GemmJob { const bf16* A; const bf16* Bw; float* Cf; bf16* Cb; int mode; };
struct GemmArgs { GemmJob job[4]; int N; int K; };

template <int MT>
__global__ __launch_bounds__(256) void gemm_bt(GemmArgs ga) {
  const GemmJob jb = ga.job[blockIdx.z];
  const int N = ga.N, K = ga.K;
  constexpr int TM = MT * 64;               // tile rows
  __shared__ __align__(16) bf16 As[TM * 64];
  __shared__ __align__(16) bf16 Bs[128 * 64];

  const int tid  = threadIdx.x;
  const int lane = tid & 63;
  const int wave = tid >> 6;
  const int wm   = (wave >> 1) * (MT * 32);
  const int wn   = (wave & 1) * 64;

  const int f   = blockIdx.y * 8 + blockIdx.x;
  const int xcd = f & 7;
  const int j   = f >> 3;
  const int bn  = j & 7;
  const int bm  = (j >> 3) * 8 + xcd;
  const int tileM = bm * TM;
  const int tileN = bn * 128;

  f32x16 acc[MT][2] = {};

  const int sr = lane >> 3;

  // Uniform 64-bit bases (SGPR pair), advanced by scalar adds per K-step.
  // Write-side pre-swizzle: source chunk sc = (lane&7) ^ sr ^ (grp&7), so
  // LDS position p of tile-row r holds chunk g = p ^ (r&7) ^ ((r>>3)&7).
  const char* pa = (const char*)(jb.A  + (size_t)tileM * K);
  const char* pb = (const char*)(jb.Bw + (size_t)tileN * K);
  unsigned int offA[MT * 2], offB[4];
#pragma unroll
  for (int l = 0; l < MT * 2; ++l) {
    int grp = wave * (MT * 2) + l;
    int sc  = (lane & 7) ^ sr ^ (grp & 7);
    offA[l] = (unsigned int)(((grp * 8 + sr) * K + sc * 8) * 2);
  }
#pragma unroll
  for (int l = 0; l < 4; ++l) {
    int grp = wave * 4 + l;
    int sc  = (lane & 7) ^ sr ^ (grp & 7);
    offB[l] = (unsigned int)(((grp * 8 + sr) * K + sc * 8) * 2);
  }

  const int half = lane >> 5;   // k-group within 16-slice
  const int rc   = lane & 31;   // row (A) / col (B) within 32-tile

  for (int k0 = 0; k0 < K; k0 += 64) {
#pragma unroll
    for (int l = 0; l < MT * 2; ++l)
      __builtin_amdgcn_global_load_lds(
          (const __attribute__((address_space(1))) void*)(pa + offA[l]),
          (__attribute__((address_space(3))) void*)&As[(wave * (MT * 2) + l) * 512],
          16, 0, 0);
#pragma unroll
    for (int l = 0; l < 4; ++l)
      __builtin_amdgcn_global_load_lds(
          (const __attribute__((address_space(1))) void*)(pb + offB[l]),
          (__attribute__((address_space(3))) void*)&Bs[(wave * 4 + l) * 512],
          16, 0, 0);
    pa += 128;  // 64 bf16 K-advance
    pb += 128;
    __syncthreads();

#pragma unroll
    for (int s = 0; s < 2; ++s) {        // two 32-k halves; ks = s*2 + kk
      bf16x8 af[MT][2], bfr[2][2];
#pragma unroll
      for (int mt = 0; mt < MT; ++mt)
#pragma unroll
        for (int kk = 0; kk < 2; ++kk) {
          int row = wm + mt * 32 + rc;
          int chunk = ((s * 2 + kk) * 2 + half) ^ (row & 7) ^ ((row >> 3) & 7);
          af[mt][kk] = *(const bf16x8*)&As[row * 64 + chunk * 8];
        }
#pragma unroll
      for (int nt = 0; nt < 2; ++nt)
#pragma unroll
        for (int kk = 0; kk < 2; ++kk) {
          int row = wn + nt * 32 + rc;
          int chunk = ((s * 2 + kk) * 2 + half) ^ (row & 7) ^ ((row >> 3) & 7);
          bfr[nt][kk] = *(const bf16x8*)&Bs[row * 64 + chunk * 8];
        }
#pragma unroll
      for (int kk = 0; kk < 2; ++kk)
#pragma unroll
        for (int mt = 0; mt < MT; ++mt)
#pragma unroll
          for (int nt = 0; nt < 2; ++nt)
            acc[mt][nt] = __builtin_amdgcn_mfma_f32_32x32x16_bf16(
                af[mt][kk], bfr[nt][kk], acc[mt][nt], 0, 0, 0);
    }
    __syncthreads();
  }

  // C/D: col = lane&31, row = (reg&3) + 8*(reg>>2) + 4*(lane>>5)
  const int cn    = rc;
  const int rbase = half * 4;
  if (jb.mode == 0) {
#pragma unroll
    for (int mt = 0; mt < MT; ++mt)
#pragma unroll
      for (int nt = 0; nt < 2; ++nt)
#pragma unroll
        for (int r = 0; r < 16; ++r) {
          int row = tileM + wm + mt * 32 + rbase + (r & 3) + 8 * (r >> 2);
          int col = tileN + wn + nt * 32 + cn;
          jb.Cf[(size_t)row * N + col] = acc[mt][nt][r];
        }
  } else if (jb.mode == 1) {
#pragma unroll
    for (int mt = 0; mt < MT; ++mt)
#pragma unroll
      for (int nt = 0; nt < 2; ++nt)
#pragma unroll
        for (int r = 0; r < 16; ++r) {
          int row = tileM + wm + mt * 32 + rbase + (r & 3) + 8 * (r >> 2);
          int col = tileN + wn + nt * 32 + cn;
          jb.Cb[(size_t)row * N + col] =
              (bf16)(1.f / (1.f + __expf(-acc[mt][nt][r])));
        }
  } else {
#pragma unroll
    for (int mt = 0; mt < MT; ++mt)
#pragma unroll
      for (int nt = 0; nt < 2; ++nt)
#pragma unroll
        for (int r = 0; r < 16; ++r) {
          int row = tileM + wm + mt * 32 + rbase + (r & 3) + 8 * (r >> 2);
          int col = tileN + wn + nt * 32 + cn;
          jb.Cb[(size_t)row * N + col] = (bf16)acc[mt][nt][r];
        }
  }
}

// ---------------------------------------------------------------------------
// Pass A: per-block partial reduction over 8 j-rows, atomic-free.
// m[j,d]=max_b K; w=exp(K-m); partial num/den summed over the block's j's.
// 256 blocks (1/CU). Thread-half h covers j in [blk*8+h*4, +4), 8 d each.
// Halves merge via LDS [idx][dt] (conflict-free), half 0 stores partials:
// part[blk][0:4096]=num(b,d), part[blk][4096:8192]=den(b,d).
// ---------------------------------------------------------------------------
__global__ __launch_bounds__(256) void reduce_kv(
    const bf16* __restrict__ Kb, const bf16* __restrict__ Vb,
    float* __restrict__ part) {
  __shared__ float lds[64 * 128];
  const int t = threadIdx.x;
  const int half = t >> 7;
  const int dt = t & 127;
  const int d = dt * 8;
  const int j0 = blockIdx.x * 8 + half * 4;
  const size_t bs = (size_t)T_ * DH_;
  float n[4][8] = {}, e[4][8] = {};
  for (int jj = j0; jj < j0 + 4; ++jj) {
    size_t off = (size_t)jj * DH_ + d;
    bf16x8 kk[4], vv[4];
#pragma unroll
    for (int b = 0; b < 4; ++b) {
      kk[b] = *(const bf16x8*)(Kb + off + b * bs);
      vv[b] = *(const bf16x8*)(Vb + off + b * bs);
    }
#pragma unroll
    for (int c = 0; c < 8; ++c) {
      float k0 = (float)kk[0][c], k1 = (float)kk[1][c];
      float k2 = (float)kk[2][c], k3 = (float)kk[3][c];
      float m = fmaxf(fmaxf(k0, k1), fmaxf(k2, k3));
      float w0 = __expf(k0 - m), w1 = __expf(k1 - m);
      float w2 = __expf(k2 - m), w3 = __expf(k3 - m);
      e[0][c] += w0; e[1][c] += w1; e[2][c] += w2; e[3][c] += w3;
      n[0][c] += w0 * (float)vv[0][c];
      n[1][c] += w1 * (float)vv[1][c];
      n[2][c] += w2 * (float)vv[2][c];
      n[3][c] += w3 * (float)vv[3][c];
    }
  }
  if (half) {
#pragma unroll
    for (int b = 0; b < 4; ++b)
#pragma unroll
      for (int c = 0; c < 8; ++c) {
        lds[(b * 8 + c) * 128 + dt] = n[b][c];
        lds[(32 + b * 8 + c) * 128 + dt] = e[b][c];
      }
  }
  __syncthreads();
  if (!half) {
    float* po = part + (size_t)blockIdx.x * 8192;
#pragma unroll
    for (int b = 0; b < 4; ++b)
#pragma unroll
      for (int c = 0; c < 8; ++c) {
        po[b * 1024 + d + c] = n[b][c] + lds[(b * 8 + c) * 128 + dt];
        po[4096 + b * 1024 + d + c] = e[b][c] + lds[(32 + b * 8 + c) * 128 + dt];
      }
  }
}

// ---------------------------------------------------------------------------
// Pass B: numden[slot] = sum over 256 blocks of part[i][slot].
// 64 blocks x 256 threads; thread-half sums 128 partials (unroll-8 ILP),
// halves merge via LDS. Coalesced: consecutive threads = consecutive slots.
// ---------------------------------------------------------------------------
__global__ __launch_bounds__(256) void finish_kv(
    const float* __restrict__ part, float* __restrict__ numden) {
  __shared__ float lds[128];
  const int t = threadIdx.x;
  const int half = t >> 7;
  const int sl = t & 127;
  const int slot = blockIdx.x * 128 + sl;
  float s = 0.f;
  for (int i = half * 128; i < half * 128 + 128; i += 8) {
#pragma unroll
    for (int u = 0; u < 8; ++u)
      s += part[(size_t)(i + u) * 8192 + slot];
  }
  if (half) lds[sl] = s;
  __syncthreads();
  if (!half) numden[slot] = s + lds[sl];
}

// ---------------------------------------------------------------------------
// Wo_b[b][m][h] = Wo[m][h] * num[b,h]/den[b,h]  (ratio folded into weight;
// exact: out[b] = (sig(Q[b]) ⊙ r[b]) @ Wo^T = sig(Q[b]) @ (Wo ⊙ r[b])^T
// since num/den are i-independent). grid (512, 4): b = blockIdx.y.
// ---------------------------------------------------------------------------
__global__ __launch_bounds__(256) void scale_wo(
    const bf16* __restrict__ Wo, const float* __restrict__ numden,
    bf16* __restrict__ out4) {
  const int b = blockIdx.y;
  size_t i = ((size_t)blockIdx.x * 256 + threadIdx.x) * 8;
  int h = (int)(i & (DH_ - 1));
  bf16x8 w = *(const bf16x8*)(Wo + i);
  const float* nu = numden + b * DH_ + h;
  const float* de = numden + 4096 + b * DH_ + h;
  float4 n0 = *(const float4*)nu;
  float4 n1 = *(const float4*)(nu + 4);
  float4 d0 = *(const float4*)de;
  float4 d1 = *(const float4*)(de + 4);
  bf16x8 o;
  o[0] = (bf16)((float)w[0] * n0.x / d0.x);
  o[1] = (bf16)((float)w[1] * n0.y / d0.y);
  o[2] = (bf16)((float)w[2] * n0.z / d0.z);
  o[3] = (bf16)((float)w[3] * n0.w / d0.w);
  o[4] = (bf16)((float)w[4] * n1.x / d1.x);
  o[5] = (bf16)((float)w[5] * n1.y / d1.y);
  o[6] = (bf16)((float)w[6] * n1.z / d1.z);
  o[7] = (bf16)((float)w[7] * n1.w / d1.w);
  *(bf16x8*)(out4 + (size_t)b * ((size_t)DM_ * DH_) + i) = o;
}

// ---------------------------------------------------------------------------
extern "C" void kernel_launch(void* const* d_in, const int* in_sizes, int n_in,
                              void* d_out, int out_size, void* d_ws, size_t ws_size,
                              hipStream_t stream) {
  const float* q  = (const float*)d_in[0];
  const float* k  = (const float*)d_in[1];
  const float* v  = (const float*)d_in[2];
  const float* Wq = (const float*)d_in[3];
  const float* Wk = (const float*)d_in[4];
  const float* Wv = (const float*)d_in[5];
  const float* Wo = (const float*)d_in[6];
  // d_in[7] = W_bias mathematically unused (exp_pos_bias == all-ones).
  float* out = (float*)d_out;

  char* ws = (char*)d_ws;
  size_t off = 0;
  auto alloc = [&](size_t bytes) {
    char* p = ws + off;
    off += (bytes + 255) & ~(size_t)255;
    return p;
  };
  const size_t actN = (size_t)MROWS * DM_;   // 8388608
  const size_t wN   = (size_t)DH_ * DM_;     // 1048576

  bf16* qb  = (bf16*)alloc(actN * 2);
  bf16* kb  = (bf16*)alloc(actN * 2);
  bf16* vb  = (bf16*)alloc(actN * 2);
  bf16* Wqb = (bf16*)alloc(wN * 2);
  bf16* Wkb = (bf16*)alloc(wN * 2);
  bf16* Wvb = (bf16*)alloc(wN * 2);
  bf16* Wob = (bf16*)alloc(wN * 2);
  bf16* Kb  = (bf16*)alloc(actN * 2);
  bf16* Vb  = (bf16*)alloc(actN * 2);
  bf16* Yb  = (bf16*)alloc(actN * 2);
  float* part = (float*)alloc((size_t)256 * 8192 * 4);   // 8 MB partials
  float* numden = (float*)alloc(8192 * 4);
  // Wob4 (4 batch-scaled Wo copies, 8MB) aliases part: part is dead after
  // finish_kv, scale_wo runs after it (stream-ordered).
  bf16* Wob4 = (bf16*)part;

  // 1) fp32 -> bf16 (activations + all 4 weights)
  CvtArgs ca;
  ca.job[0] = {q,  qb,  (int)(actN / 4)};
  ca.job[1] = {k,  kb,  (int)(actN / 4)};
  ca.job[2] = {v,  vb,  (int)(actN / 4)};
  ca.job[3] = {Wq, Wqb, (int)(wN / 4)};
  ca.job[4] = {Wk, Wkb, (int)(wN / 4)};
  ca.job[5] = {Wv, Wvb, (int)(wN / 4)};
  ca.job[6] = {Wo, Wob, (int)(wN / 4)};
  cvt_kernel<<<dim3(actN / 4 / 2048, 7), 256, 0, stream>>>(ca);

  // 2) merged K/V/Q projections (async bf16 staging; Q epilogue = sigmoid)
  GemmArgs g1;
  g1.N = DH_; g1.K = DM_;
  g1.job[0] = {kb, Wkb, nullptr, Kb, 2};
  g1.job[1] = {vb, Wvb, nullptr, Vb, 2};
  g1.job[2] = {qb, Wqb, nullptr, Yb, 1};
  g1.job[3] = {nullptr, nullptr, nullptr, nullptr, 0};
  gemm_bt<2><<<dim3(8, MROWS / 128, 3), 256, 0, stream>>>(g1);

  // 3) two-pass atomic-free reduction
  reduce_kv<<<dim3(256), 256, 0, stream>>>(Kb, Vb, part);
  finish_kv<<<dim3(64), 256, 0, stream>>>(part, numden);

  // 4) fold ratio into per-batch Wo copies
  scale_wo<<<dim3(512, 4), 256, 0, stream>>>(Wob, numden, Wob4);

  // 5) out[b] = sig(Q[b]) @ (Wo ⊙ r[b])^T  — 4 per-batch jobs, fp32 out,
  //    64-row tiles (MT=1): 1024 blocks = 4/CU for latency hiding.
  GemmArgs g2;
  g2.N = DM_; g2.K = DH_;
  for (int b = 0; b < 4; ++b) {
    g2.job[b] = {Yb + (size_t)b * ((size_t)T_ * DH_),
                 Wob4 + (size_t)b * wN,
                 out + (size_t)b * ((size_t)T_ * DM_),
                 nullptr, 0};
  }
  gemm_bt<1><<<dim3(8, 32, 4), 256, 0, stream>>>(g2);
}